// Round 16
// baseline (101.546 us; speedup 1.0000x reference)
//
#include <hip/hip_runtime.h>
#include <hip/hip_bf16.h>

#define Hh   200
#define Ww   200
#define CIN  490
#define OCN  98      // 2*K*K
#define KK   7
#define COUT 10
#define NROIS 512
#define PIX  8

#define PH   202     // padded H
#define PW   202     // padded W
#define PC   512     // padded channels
#define NPIX (Hh * Ww)          // 40000
#define KCN  16                 // k-chunks of 32 per tap (512/32)
#define NF   7                  // N fragments (112 cols)
#define NUNITS 144              // 16 kc * 9 taps (kc-major: u = kc*9 + tap)
#define HGRAN  18               // granules per k-half (72 units / 4)
#define HALF_SHORTS (8 * 3584)  // LDS shorts per k-half (57,344 B)

#define FEAT_BLOCKS 10201       // (202*202*64)/256
#define W_BLOCKS    2016        // (144*7*512)/256

typedef __attribute__((ext_vector_type(8))) short short8;
typedef __attribute__((ext_vector_type(4))) float float4v;

// ---------------------------------------------------------------------------
// Merged pack kernel: blocks [0, FEAT_BLOCKS) pack features fp32
// [200,200,490] -> bf16 [202,202,512] (zero borders+pad); blocks
// [FEAT_BLOCKS, ..) pack weights into MFMA B-fragment order, kc-major:
// bp[u][f][lane][j], u = kc*9 + tap, k = kc*32 + (lane>>4)*8 + j,
// n = f*16 + (lane&15).
// ---------------------------------------------------------------------------
__global__ __launch_bounds__(256) void pack_all_kernel(
    const float* __restrict__ feat, const float* __restrict__ w,
    __hip_bfloat16* __restrict__ pf, __hip_bfloat16* __restrict__ bp)
{
    if (blockIdx.x < FEAT_BLOCKS) {
        int tid = blockIdx.x * 256 + threadIdx.x;
        int c8  = (tid & 63) * 8;
        int pix = tid >> 6;
        int py = pix / PW, px = pix % PW;
        __hip_bfloat16* dst = pf + (size_t)pix * PC + c8;
        bool interior = (py >= 1 && py <= Hh && px >= 1 && px <= Ww);

        __hip_bfloat16 v[8];
        if (interior && c8 + 8 <= CIN) {
            const float* s = feat + ((size_t)(py - 1) * Ww + (px - 1)) * CIN + c8;
#pragma unroll
            for (int q = 0; q < 4; ++q) {
                float2 f2 = *reinterpret_cast<const float2*>(s + q * 2);
                v[q * 2]     = __float2bfloat16(f2.x);
                v[q * 2 + 1] = __float2bfloat16(f2.y);
            }
        } else {
            const float* s = interior ? feat + ((size_t)(py - 1) * Ww + (px - 1)) * CIN : nullptr;
#pragma unroll
            for (int j = 0; j < 8; ++j) {
                float val = (interior && (c8 + j) < CIN) ? s[c8 + j] : 0.f;
                v[j] = __float2bfloat16(val);
            }
        }
        *reinterpret_cast<short8*>(dst) = *reinterpret_cast<short8*>(v);
    } else {
        int idx = (blockIdx.x - FEAT_BLOCKS) * 256 + threadIdx.x;
        int j = idx & 7;
        int l = (idx >> 3) & 63;
        int f = (idx >> 9) % NF;
        int u = idx / (NF * 512);        // kc*9 + tap
        int kc = u / 9, tap = u % 9;
        int k = kc * 32 + ((l >> 4) * 8) + j;
        int n = f * 16 + (l & 15);
        float val = (k < CIN && n < OCN) ? w[((size_t)tap * CIN + k) * OCN + n] : 0.f;
        bp[idx] = __float2bfloat16(val);
    }
}

// ---------------------------------------------------------------------------
// Implicit-GEMM 3x3 conv via MFMA, LDS-shared B, K-SPLIT waves with EARLY
// separate A-prefetch registers (the untested r8+bounds combination).
// Block = 640 threads (10 waves); grid = 250; bijective XCD swizzle.
// Wave (mpos, ks): mpos owns M rows [mpos*32, +32) (MR=2); ks owns k-units
// [ks*72, +72) (18 granules of 4). Each B ds_read feeds 2 MFMAs -> HALF of
// r7's LDS reads at identical occupancy/balance.
// All prefetch (B reg-stage + A next-regs) issues BEFORE the compute phase,
// so the barrier's vmcnt(0) drain finds loads already covered (r11's
// in-place reloads issued at compute tail and exposed the drain; r8's
// version of this spilled without the launch-bounds VGPR headroom).
// Epilogue: ks=1 partial accs -> LDS -> ks=0 adds and stores.
// ---------------------------------------------------------------------------
__global__ __launch_bounds__(640, 2) void conv_mfma_kernel(
    const short* __restrict__ pf,   // padfeat bf16 [202*202*512]
    const short* __restrict__ bp,   // bpack bf16 [144*7*64*8]
    float* __restrict__ om)         // [40000,98]
{
    __shared__ short bsm[2 * HALF_SHORTS];  // 114,688 B

    // bijective XCD chunked swizzle: nwg=250, q=31, r=2
    int orig = blockIdx.x;
    int xcd = orig & 7;
    int pos = orig >> 3;
    int blk = ((xcd < 2) ? xcd * 32 : 64 + (xcd - 2) * 31) + pos;

    int l = threadIdx.x & 63;
    int w = threadIdx.x >> 6;        // wave 0..9
    int mpos = w % 5;                // 0..4
    int ks = w / 5;                  // 0..1 (k-half)
    int ubase = ks * 72;             // first unit of this half
    int m0 = blk * 160 + mpos * 32;

    // A base pointers for the 2 M-frags
    const short* abase0;
    const short* abase1;
    {
        int row0 = m0 + (l & 15);
        int row1 = m0 + 16 + (l & 15);
        int y0 = row0 / Ww, x0 = row0 % Ww;
        int y1 = row1 / Ww, x1 = row1 % Ww;
        abase0 = pf + ((size_t)(y0 * PW + x0) * PC) + ((l >> 4) * 8);
        abase1 = pf + ((size_t)(y1 * PW + x1) * PC) + ((l >> 4) * 8);
    }

    float4v acc[2][NF];
#pragma unroll
    for (int r = 0; r < 2; ++r)
#pragma unroll
        for (int f = 0; f < NF; ++f) acc[r][f] = (float4v){0.f, 0.f, 0.f, 0.f};

    // A offset (in shorts) for k-unit u = kc*9 + tap
    auto aOff = [&](int u) -> int {
        int kc = u / 9, tap = u - kc * 9;
        int ky = tap / 3, kx = tap - ky * 3;
        return (ky * PW + kx) * PC + kc * 32;
    };
    int lbase = ks * HALF_SHORTS;    // this half's LDS base (shorts)

    // ---- prologue: stage own half's granule 0 (28 slot-writes, 5 waves) ----
#pragma unroll
    for (int s = 0; s < 6; ++s) {
        int i = mpos + s * 5;
        if (i < 28) {
            int uu = ubase + i / 7, f = i % 7;
            short8 v = *reinterpret_cast<const short8*>(
                bp + ((size_t)(uu * NF + f)) * 512 + l * 8);
            *reinterpret_cast<short8*>(
                &bsm[lbase + (uu & 7) * 3584 + f * 512 + l * 8]) = v;
        }
    }
    // prefetch A for granule 0
    short8 a00 = *reinterpret_cast<const short8*>(abase0 + aOff(ubase + 0));
    short8 a01 = *reinterpret_cast<const short8*>(abase0 + aOff(ubase + 1));
    short8 a02 = *reinterpret_cast<const short8*>(abase0 + aOff(ubase + 2));
    short8 a03 = *reinterpret_cast<const short8*>(abase0 + aOff(ubase + 3));
    short8 a10 = *reinterpret_cast<const short8*>(abase1 + aOff(ubase + 0));
    short8 a11 = *reinterpret_cast<const short8*>(abase1 + aOff(ubase + 1));
    short8 a12 = *reinterpret_cast<const short8*>(abase1 + aOff(ubase + 2));
    short8 a13 = *reinterpret_cast<const short8*>(abase1 + aOff(ubase + 3));
    __syncthreads();

    for (int g = 0; g < HGRAN; ++g) {
        bool more = (g < HGRAN - 1);
        int u0n = ubase + (g + 1) * 4;

        // 1) issue B global loads for own half's granule g+1 (6 reg slots)
        short8 st0, st1, st2, st3, st4, st5;
        int off0 = -1, off1 = -1, off2 = -1, off3 = -1, off4 = -1, off5 = -1;
        if (more) {
#define STAGE_LOAD(S, STV, OFFV)                                               \
            {                                                                  \
                int i = mpos + (S) * 5;                                        \
                if (i < 28) {                                                  \
                    int uu = u0n + i / 7, f = i % 7;                           \
                    STV = *reinterpret_cast<const short8*>(                    \
                        bp + ((size_t)(uu * NF + f)) * 512 + l * 8);           \
                    OFFV = lbase + (uu & 7) * 3584 + f * 512 + l * 8;          \
                }                                                              \
            }
            STAGE_LOAD(0, st0, off0)
            STAGE_LOAD(1, st1, off1)
            STAGE_LOAD(2, st2, off2)
            STAGE_LOAD(3, st3, off3)
            STAGE_LOAD(4, st4, off4)
            STAGE_LOAD(5, st5, off5)
#undef STAGE_LOAD
        }
        // 2) issue A loads for granule g+1 EARLY into separate regs
        short8 n00, n01, n02, n03, n10, n11, n12, n13;
        if (more) {
            n00 = *reinterpret_cast<const short8*>(abase0 + aOff(u0n + 0));
            n01 = *reinterpret_cast<const short8*>(abase0 + aOff(u0n + 1));
            n02 = *reinterpret_cast<const short8*>(abase0 + aOff(u0n + 2));
            n03 = *reinterpret_cast<const short8*>(abase0 + aOff(u0n + 3));
            n10 = *reinterpret_cast<const short8*>(abase1 + aOff(u0n + 0));
            n11 = *reinterpret_cast<const short8*>(abase1 + aOff(u0n + 1));
            n12 = *reinterpret_cast<const short8*>(abase1 + aOff(u0n + 2));
            n13 = *reinterpret_cast<const short8*>(abase1 + aOff(u0n + 3));
        }

        // 3) compute granule g: 4 units x 7 frags x 2 M = 56 MFMA
        int u0 = ubase + g * 4;
#define UNIT_STEP(J, AR0, AR1)                                                  \
        {                                                                       \
            int sbase = lbase + ((u0 + J) & 7) * 3584 + l * 8;                  \
            _Pragma("unroll")                                                   \
            for (int f = 0; f < NF; ++f) {                                      \
                short8 b = *reinterpret_cast<short8*>(&bsm[sbase + f * 512]);   \
                acc[0][f] = __builtin_amdgcn_mfma_f32_16x16x32_bf16(            \
                    AR0, b, acc[0][f], 0, 0, 0);                                \
                acc[1][f] = __builtin_amdgcn_mfma_f32_16x16x32_bf16(            \
                    AR1, b, acc[1][f], 0, 0, 0);                                \
            }                                                                   \
        }
        UNIT_STEP(0, a00, a10)
        UNIT_STEP(1, a01, a11)
        UNIT_STEP(2, a02, a12)
        UNIT_STEP(3, a03, a13)
#undef UNIT_STEP

        // 4) write staged B to LDS
        if (off0 >= 0) *reinterpret_cast<short8*>(&bsm[off0]) = st0;
        if (off1 >= 0) *reinterpret_cast<short8*>(&bsm[off1]) = st1;
        if (off2 >= 0) *reinterpret_cast<short8*>(&bsm[off2]) = st2;
        if (off3 >= 0) *reinterpret_cast<short8*>(&bsm[off3]) = st3;
        if (off4 >= 0) *reinterpret_cast<short8*>(&bsm[off4]) = st4;
        if (off5 >= 0) *reinterpret_cast<short8*>(&bsm[off5]) = st5;
        // 5) rotate A prefetch
        if (more) {
            a00 = n00; a01 = n01; a02 = n02; a03 = n03;
            a10 = n10; a11 = n11; a12 = n12; a13 = n13;
        }
        __syncthreads();
    }

    // ---- epilogue: reduce the two k-halves, then store ----
    float* lred = (float*)bsm;
    if (ks == 1) {
#pragma unroll
        for (int r = 0; r < 2; ++r)
#pragma unroll
            for (int f = 0; f < NF; ++f) {
                int idx = (((mpos * 2 + r) * NF + f) * 64 + l) * 4;
                *reinterpret_cast<float4v*>(&lred[idx]) = acc[r][f];
            }
    }
    __syncthreads();
    if (ks == 0) {
        int n = l & 15;
#pragma unroll
        for (int r = 0; r < 2; ++r) {
            int rbase = m0 + r * 16 + ((l >> 4) * 4);
#pragma unroll
            for (int f = 0; f < NF; ++f) {
                int idx = (((mpos * 2 + r) * NF + f) * 64 + l) * 4;
                float4v other = *reinterpret_cast<float4v*>(&lred[idx]);
                float4v tot = acc[r][f] + other;
                int col = f * 16 + n;
                if (col < OCN) {
#pragma unroll
                    for (int j = 0; j < 4; ++j)
                        om[(size_t)(rbase + j) * OCN + col] = tot[j];
                }
            }
        }
    }
}

// ---------------------------------------------------------------------------
// Fallback fp32 conv (used only if ws too small for the MFMA path).
// ---------------------------------------------------------------------------
__global__ __launch_bounds__(256) void conv3x3_kernel(
    const float* __restrict__ feat, const float* __restrict__ w,
    const float* __restrict__ zero, float* __restrict__ om)
{
    int idx = blockIdx.x * blockDim.x + threadIdx.x;
    if (idx >= Hh * (Ww / PIX) * OCN) return;
    int oc = idx % OCN;
    int g  = idx / OCN;
    int x0 = (g % (Ww / PIX)) * PIX;
    int y  = g / (Ww / PIX);

    float acc[PIX];
#pragma unroll
    for (int p = 0; p < PIX; ++p) acc[p] = 0.f;

    for (int ky = 0; ky < 3; ++ky) {
        int yy = y + ky - 1;
        if (yy < 0 || yy >= Hh) continue;
        const float* frow = feat + (size_t)yy * Ww * CIN;
        for (int kx = 0; kx < 3; ++kx) {
            const float* wp = w + ((ky * 3 + kx) * CIN) * OCN + oc;
            const float* fp[PIX];
#pragma unroll
            for (int p = 0; p < PIX; ++p) {
                int xx = x0 + p + kx - 1;
                fp[p] = (xx >= 0 && xx < Ww) ? (frow + (size_t)xx * CIN) : zero;
            }
            for (int ic = 0; ic < CIN; ic += 2) {
                float w0 = wp[ic * OCN];
                float w1 = wp[(ic + 1) * OCN];
#pragma unroll
                for (int p = 0; p < PIX; ++p) {
                    float2 f = *reinterpret_cast<const float2*>(fp[p] + ic);
                    acc[p] = fmaf(f.x, w0, acc[p]);
                    acc[p] = fmaf(f.y, w1, acc[p]);
                }
            }
        }
    }
    float* orow = om + ((size_t)y * Ww + x0) * OCN + oc;
#pragma unroll
    for (int p = 0; p < PIX; ++p) orow[p * OCN] = acc[p];
}

// ---------------------------------------------------------------------------
// Bilinear setup matching the reference exactly.
// ---------------------------------------------------------------------------
__device__ __forceinline__ void bilin_setup(float y, float x,
    int& i00, int& i01, int& i10, int& i11,
    float& w00, float& w01, float& w10, float& w11)
{
    y = fminf(fmaxf(y, 0.f), 199.f);
    x = fminf(fmaxf(x, 0.f), 199.f);
    float y0f = floorf(y), x0f = floorf(x);
    int y0 = (int)y0f, x0i = (int)x0f;
    int y1 = min(y0 + 1, 199), x1 = min(x0i + 1, 199);
    float wy = y - y0f, wx = x - x0f;
    i00 = y0 * Ww + x0i;  i01 = y0 * Ww + x1;
    i10 = y1 * Ww + x0i;  i11 = y1 * Ww + x1;
    w00 = (1.f - wy) * (1.f - wx);
    w01 = (1.f - wy) * wx;
    w10 = wy * (1.f - wx);
    w11 = wy * wx;
}

// ---------------------------------------------------------------------------
// Per-ROI two-stage deformable PS-RoI pooling. Stage 2 float2-vectorized.
// ---------------------------------------------------------------------------
__global__ __launch_bounds__(256) void psroi_kernel(
    const float* __restrict__ feat, const float* __restrict__ rois,
    const float* __restrict__ om, float* __restrict__ out)
{
    int n = blockIdx.x;
    int t = threadIdx.x;

    float x1 = rois[n * 5 + 1], y1 = rois[n * 5 + 2];
    float x2 = rois[n * 5 + 3], y2 = rois[n * 5 + 4];
    float rw = x2 - x1 + 1.0f, rh = y2 - y1 + 1.0f;
    float fx1 = x1 * 0.0625f, fy1 = y1 * 0.0625f;
    float bw = (rw * 0.0625f) / 7.0f;
    float bh = (rh * 0.0625f) / 7.0f;

    __shared__ float offs[49][2];

    if (t < 49) {
        int bi = t / 7, bj = t % 7;
        float ax = 0.f, ay = 0.f;
#pragma unroll
        for (int ss = 0; ss < 4; ++ss) {
            float sj = ((float)(ss & 1) + 0.5f) * 0.5f;
            float si = ((float)(ss >> 1) + 0.5f) * 0.5f;
            float gx = fx1 + ((float)bj + sj) * bw;
            float gy = fy1 + ((float)bi + si) * bh;
            int i00, i01, i10, i11; float w00, w01, w10, w11;
            bilin_setup(gy, gx, i00, i01, i10, i11, w00, w01, w10, w11);
            int c0 = t * 2;
            const float* p00 = om + (size_t)i00 * OCN + c0;
            const float* p01 = om + (size_t)i01 * OCN + c0;
            const float* p10 = om + (size_t)i10 * OCN + c0;
            const float* p11 = om + (size_t)i11 * OCN + c0;
            ax += w00 * p00[0] + w01 * p01[0] + w10 * p10[0] + w11 * p11[0];
            ay += w00 * p00[1] + w01 * p01[1] + w10 * p10[1] + w11 * p11[1];
        }
        offs[t][0] = ax * 0.25f * rw * 0.1f * 0.0625f;
        offs[t][1] = ay * 0.25f * rh * 0.1f * 0.0625f;
    }
    __syncthreads();

    if (t < 245) {                       // 49 bins x 5 channel-pairs
        int bin = t / 5, cp = t % 5;
        int bi = bin / 7, bj = bin % 7;
        float dx = offs[bin][0], dy = offs[bin][1];
        int ch0 = bin * COUT + cp * 2;   // even -> 8B-aligned everywhere
        float accx = 0.f, accy = 0.f;
#pragma unroll
        for (int ss = 0; ss < 4; ++ss) {
            float sj = ((float)(ss & 1) + 0.5f) * 0.5f;
            float si = ((float)(ss >> 1) + 0.5f) * 0.5f;
            float gx = fx1 + ((float)bj + sj) * bw + dx;
            float gy = fy1 + ((float)bi + si) * bh + dy;
            int i00, i01, i10, i11; float w00, w01, w10, w11;
            bilin_setup(gy, gx, i00, i01, i10, i11, w00, w01, w10, w11);
            float2 v00 = *reinterpret_cast<const float2*>(feat + (size_t)i00 * CIN + ch0);
            float2 v01 = *reinterpret_cast<const float2*>(feat + (size_t)i01 * CIN + ch0);
            float2 v10 = *reinterpret_cast<const float2*>(feat + (size_t)i10 * CIN + ch0);
            float2 v11 = *reinterpret_cast<const float2*>(feat + (size_t)i11 * CIN + ch0);
            accx += w00 * v00.x + w01 * v01.x + w10 * v10.x + w11 * v11.x;
            accy += w00 * v00.y + w01 * v01.y + w10 * v10.y + w11 * v11.y;
        }
        float2 res = {accx * 0.25f, accy * 0.25f};
        *reinterpret_cast<float2*>(
            out + (size_t)n * (KK * KK * COUT) + bin * COUT + cp * 2) = res;
    }
}

extern "C" void kernel_launch(void* const* d_in, const int* in_sizes, int n_in,
                              void* d_out, int out_size, void* d_ws, size_t ws_size,
                              hipStream_t stream) {
    const float* feat = (const float*)d_in[0];   // [1,200,200,490]
    const float* rois = (const float*)d_in[1];   // [512,5]
    const float* w    = (const float*)d_in[2];   // [3,3,490,98]
    float* out = (float*)d_out;                  // [512,7,7,10]

    const size_t OM_BYTES = (size_t)NPIX * OCN * 4;                 // 15,680,000
    const size_t BP_BYTES = (size_t)NUNITS * NF * 64 * 8 * 2;       // 1,032,192
    const size_t PF_BYTES = (size_t)PH * PW * PC * 2;               // 41,783,296
    const size_t NEEDED = OM_BYTES + BP_BYTES + PF_BYTES;

    if (ws_size >= NEEDED) {
        float* om = (float*)d_ws;
        __hip_bfloat16* bp = (__hip_bfloat16*)((char*)d_ws + OM_BYTES);
        __hip_bfloat16* pf = (__hip_bfloat16*)((char*)d_ws + OM_BYTES + BP_BYTES);

        pack_all_kernel<<<FEAT_BLOCKS + W_BLOCKS, 256, 0, stream>>>(feat, w, pf, bp);
        conv_mfma_kernel<<<250, 640, 0, stream>>>(
            (const short*)pf, (const short*)bp, om);
        psroi_kernel<<<NROIS, 256, 0, stream>>>(feat, rois, om, out);
    } else {
        // fallback fp32 path
        float* zero = (float*)d_ws;
        float* om   = (float*)d_ws + 1024;
        hipMemsetAsync(d_ws, 0, 4096, stream);
        int convThreads = Hh * (Ww / PIX) * OCN;
        conv3x3_kernel<<<(convThreads + 255) / 256, 256, 0, stream>>>(feat, w, zero, om);
        psroi_kernel<<<NROIS, 256, 0, stream>>>(feat, rois, om, out);
    }
}

// Round 17
// 89.021 us; speedup vs baseline: 1.1407x; 1.1407x over previous
//
#include <hip/hip_runtime.h>
#include <hip/hip_bf16.h>

#define Hh   200
#define Ww   200
#define CIN  490
#define OCN  98      // 2*K*K
#define KK   7
#define COUT 10
#define NROIS 512
#define PIX  8

#define PH   202     // padded H
#define PW   202     // padded W
#define PC   512     // padded channels
#define NPIX (Hh * Ww)          // 40000
#define KCN  16                 // k-chunks of 32 per tap (512/32)
#define NF   7                  // N fragments (112 cols)
#define NUNITS 144              // 16 kc * 9 taps (kc-major: u = kc*9 + tap)
#define NGRAN  36               // 144 / 4 units per granule

#define FEAT_BLOCKS 10201       // (202*202*64)/256
#define W_BLOCKS    2016        // (144*7*512)/256

typedef __attribute__((ext_vector_type(8))) short short8;
typedef __attribute__((ext_vector_type(4))) float float4v;

// ---------------------------------------------------------------------------
// Merged pack kernel: blocks [0, FEAT_BLOCKS) pack features fp32
// [200,200,490] -> bf16 [202,202,512] (zero borders+pad); blocks
// [FEAT_BLOCKS, FEAT_BLOCKS+W_BLOCKS) pack weights into MFMA B-fragment
// order, kc-major: bp[u][f][lane][j], u = kc*9 + tap, with
// k = kc*32 + (lane>>4)*8 + j, n = f*16 + (lane&15).
// ---------------------------------------------------------------------------
__global__ __launch_bounds__(256) void pack_all_kernel(
    const float* __restrict__ feat, const float* __restrict__ w,
    __hip_bfloat16* __restrict__ pf, __hip_bfloat16* __restrict__ bp)
{
    if (blockIdx.x < FEAT_BLOCKS) {
        int tid = blockIdx.x * 256 + threadIdx.x;
        int c8  = (tid & 63) * 8;
        int pix = tid >> 6;
        int py = pix / PW, px = pix % PW;
        __hip_bfloat16* dst = pf + (size_t)pix * PC + c8;
        bool interior = (py >= 1 && py <= Hh && px >= 1 && px <= Ww);

        __hip_bfloat16 v[8];
        if (interior && c8 + 8 <= CIN) {
            const float* s = feat + ((size_t)(py - 1) * Ww + (px - 1)) * CIN + c8;
#pragma unroll
            for (int q = 0; q < 4; ++q) {
                float2 f2 = *reinterpret_cast<const float2*>(s + q * 2);
                v[q * 2]     = __float2bfloat16(f2.x);
                v[q * 2 + 1] = __float2bfloat16(f2.y);
            }
        } else {
            const float* s = interior ? feat + ((size_t)(py - 1) * Ww + (px - 1)) * CIN : nullptr;
#pragma unroll
            for (int j = 0; j < 8; ++j) {
                float val = (interior && (c8 + j) < CIN) ? s[c8 + j] : 0.f;
                v[j] = __float2bfloat16(val);
            }
        }
        *reinterpret_cast<short8*>(dst) = *reinterpret_cast<short8*>(v);
    } else {
        int idx = (blockIdx.x - FEAT_BLOCKS) * 256 + threadIdx.x;
        int j = idx & 7;
        int l = (idx >> 3) & 63;
        int f = (idx >> 9) % NF;
        int u = idx / (NF * 512);        // kc*9 + tap
        int kc = u / 9, tap = u % 9;
        int k = kc * 32 + ((l >> 4) * 8) + j;
        int n = f * 16 + (l & 15);
        float val = (k < CIN && n < OCN) ? w[((size_t)tap * CIN + k) * OCN + n] : 0.f;
        bp[idx] = __float2bfloat16(val);
    }
}

// ---------------------------------------------------------------------------
// Implicit-GEMM 3x3 conv via MFMA with LDS-shared B (r7 EXACT — proven 64us).
// Block = 640 threads (10 waves); wave = M=16 x N=112 (7 frags);
// block M = 160; grid = 250 (exact), bijective XCD-chunked swizzle.
// kc-major unit order (u = kc*9 + tap): the 3 kx-shifted re-reads of each
// padfeat row stripe land within ~1 granule (L1/L2-resident) -> FETCH 26MB.
// B double-buffered in LDS ring of 8 x 7168 B; B reg-staged
// issue-early/write-late; A prefetched one granule ahead.
// Measured: LDS pipe ~87% busy -> structural ceiling of this 2-phase form.
// ---------------------------------------------------------------------------
__global__ __launch_bounds__(640) void conv_mfma_kernel(
    const short* __restrict__ pf,   // padfeat bf16 [202*202*512]
    const short* __restrict__ bp,   // bpack bf16 [144*7*64*8]
    float* __restrict__ om)         // [40000,98]
{
    __shared__ short bsm[8 * 3584];  // 8 unit-slots x 7168 B = 57,344 B

    // bijective XCD chunked swizzle: nwg=250, q=31, r=2
    int orig = blockIdx.x;
    int xcd = orig & 7;
    int pos = orig >> 3;
    int blk = ((xcd < 2) ? xcd * 32 : 64 + (xcd - 2) * 31) + pos;

    int l = threadIdx.x & 63;
    int w = threadIdx.x >> 6;        // wave 0..9
    int m0 = blk * 160 + w * 16;

    int row = m0 + (l & 15);
    int y = row / Ww, x = row % Ww;
    const short* abase = pf + ((size_t)(y * PW + x) * PC) + ((l >> 4) * 8);

    float4v acc[NF];
#pragma unroll
    for (int f = 0; f < NF; ++f) acc[f] = (float4v){0.f, 0.f, 0.f, 0.f};

    // A offset (in shorts) for k-unit u = kc*9 + tap
    auto aOff = [&](int u) -> int {
        int kc = u / 9, tap = u - kc * 9;
        int ky = tap / 3, kx = tap - ky * 3;
        return (ky * PW + kx) * PC + kc * 32;
    };

    // ---- prologue: stage granule 0 (units 0..3, 28 slot-writes) ----
#pragma unroll
    for (int s = 0; s < 3; ++s) {
        int i = w + s * 10;
        if (i < 28) {
            int u = i / 7, f = i % 7;
            short8 v = *reinterpret_cast<const short8*>(
                bp + ((size_t)(u * NF + f)) * 512 + l * 8);
            *reinterpret_cast<short8*>(&bsm[(u & 7) * 3584 + f * 512 + l * 8]) = v;
        }
    }
    // prefetch A for granule 0
    short8 a0 = *reinterpret_cast<const short8*>(abase + aOff(0));
    short8 a1 = *reinterpret_cast<const short8*>(abase + aOff(1));
    short8 a2 = *reinterpret_cast<const short8*>(abase + aOff(2));
    short8 a3 = *reinterpret_cast<const short8*>(abase + aOff(3));
    __syncthreads();

    for (int g = 0; g < NGRAN; ++g) {
        bool more = (g < NGRAN - 1);
        int u0n = (g + 1) * 4;

        // 1) issue B global loads for granule g+1 (regs, named slots)
        short8 st0, st1, st2;
        int off0 = -1, off1 = -1, off2 = -1;
        if (more) {
            {
                int i = w;                 // < 10, always < 28
                int uu = u0n + i / 7, f = i % 7;
                st0 = *reinterpret_cast<const short8*>(
                    bp + ((size_t)(uu * NF + f)) * 512 + l * 8);
                off0 = (uu & 7) * 3584 + f * 512 + l * 8;
            }
            {
                int i = w + 10;            // < 20, always < 28
                int uu = u0n + i / 7, f = i % 7;
                st1 = *reinterpret_cast<const short8*>(
                    bp + ((size_t)(uu * NF + f)) * 512 + l * 8);
                off1 = (uu & 7) * 3584 + f * 512 + l * 8;
            }
            if (w + 20 < 28) {
                int i = w + 20;
                int uu = u0n + i / 7, f = i % 7;
                st2 = *reinterpret_cast<const short8*>(
                    bp + ((size_t)(uu * NF + f)) * 512 + l * 8);
                off2 = (uu & 7) * 3584 + f * 512 + l * 8;
            }
        }
        // 2) issue A loads for granule g+1
        short8 n0, n1, n2, n3;
        if (more) {
            n0 = *reinterpret_cast<const short8*>(abase + aOff(u0n + 0));
            n1 = *reinterpret_cast<const short8*>(abase + aOff(u0n + 1));
            n2 = *reinterpret_cast<const short8*>(abase + aOff(u0n + 2));
            n3 = *reinterpret_cast<const short8*>(abase + aOff(u0n + 3));
        }

        // 3) compute granule g (4 units x 7 frags)
        int u0 = g * 4;
#define COMPUTE_UNIT(J, AREG)                                                   \
        {                                                                       \
            int sbase = ((u0 + J) & 7) * 3584 + l * 8;                          \
            _Pragma("unroll")                                                   \
            for (int f = 0; f < NF; ++f) {                                      \
                short8 b = *reinterpret_cast<short8*>(&bsm[sbase + f * 512]);   \
                acc[f] = __builtin_amdgcn_mfma_f32_16x16x32_bf16(               \
                    AREG, b, acc[f], 0, 0, 0);                                  \
            }                                                                   \
        }
        COMPUTE_UNIT(0, a0)
        COMPUTE_UNIT(1, a1)
        COMPUTE_UNIT(2, a2)
        COMPUTE_UNIT(3, a3)
#undef COMPUTE_UNIT

        // 4) write staged B to LDS
        if (off0 >= 0) *reinterpret_cast<short8*>(&bsm[off0]) = st0;
        if (off1 >= 0) *reinterpret_cast<short8*>(&bsm[off1]) = st1;
        if (off2 >= 0) *reinterpret_cast<short8*>(&bsm[off2]) = st2;
        // 5) rotate A prefetch
        if (more) { a0 = n0; a1 = n1; a2 = n2; a3 = n3; }
        __syncthreads();
    }

    // epilogue: store C
    int n = l & 15;
    int rbase = m0 + ((l >> 4) * 4);
#pragma unroll
    for (int f = 0; f < NF; ++f) {
        int col = f * 16 + n;
        if (col < OCN) {
#pragma unroll
            for (int j = 0; j < 4; ++j)
                om[(size_t)(rbase + j) * OCN + col] = acc[f][j];
        }
    }
}

// ---------------------------------------------------------------------------
// Fallback fp32 conv (used only if ws too small for the MFMA path).
// ---------------------------------------------------------------------------
__global__ __launch_bounds__(256) void conv3x3_kernel(
    const float* __restrict__ feat, const float* __restrict__ w,
    const float* __restrict__ zero, float* __restrict__ om)
{
    int idx = blockIdx.x * blockDim.x + threadIdx.x;
    if (idx >= Hh * (Ww / PIX) * OCN) return;
    int oc = idx % OCN;
    int g  = idx / OCN;
    int x0 = (g % (Ww / PIX)) * PIX;
    int y  = g / (Ww / PIX);

    float acc[PIX];
#pragma unroll
    for (int p = 0; p < PIX; ++p) acc[p] = 0.f;

    for (int ky = 0; ky < 3; ++ky) {
        int yy = y + ky - 1;
        if (yy < 0 || yy >= Hh) continue;
        const float* frow = feat + (size_t)yy * Ww * CIN;
        for (int kx = 0; kx < 3; ++kx) {
            const float* wp = w + ((ky * 3 + kx) * CIN) * OCN + oc;
            const float* fp[PIX];
#pragma unroll
            for (int p = 0; p < PIX; ++p) {
                int xx = x0 + p + kx - 1;
                fp[p] = (xx >= 0 && xx < Ww) ? (frow + (size_t)xx * CIN) : zero;
            }
            for (int ic = 0; ic < CIN; ic += 2) {
                float w0 = wp[ic * OCN];
                float w1 = wp[(ic + 1) * OCN];
#pragma unroll
                for (int p = 0; p < PIX; ++p) {
                    float2 f = *reinterpret_cast<const float2*>(fp[p] + ic);
                    acc[p] = fmaf(f.x, w0, acc[p]);
                    acc[p] = fmaf(f.y, w1, acc[p]);
                }
            }
        }
    }
    float* orow = om + ((size_t)y * Ww + x0) * OCN + oc;
#pragma unroll
    for (int p = 0; p < PIX; ++p) orow[p * OCN] = acc[p];
}

// ---------------------------------------------------------------------------
// Bilinear setup matching the reference exactly.
// ---------------------------------------------------------------------------
__device__ __forceinline__ void bilin_setup(float y, float x,
    int& i00, int& i01, int& i10, int& i11,
    float& w00, float& w01, float& w10, float& w11)
{
    y = fminf(fmaxf(y, 0.f), 199.f);
    x = fminf(fmaxf(x, 0.f), 199.f);
    float y0f = floorf(y), x0f = floorf(x);
    int y0 = (int)y0f, x0i = (int)x0f;
    int y1 = min(y0 + 1, 199), x1 = min(x0i + 1, 199);
    float wy = y - y0f, wx = x - x0f;
    i00 = y0 * Ww + x0i;  i01 = y0 * Ww + x1;
    i10 = y1 * Ww + x0i;  i11 = y1 * Ww + x1;
    w00 = (1.f - wy) * (1.f - wx);
    w01 = (1.f - wy) * wx;
    w10 = wy * (1.f - wx);
    w11 = wy * wx;
}

// ---------------------------------------------------------------------------
// Per-ROI two-stage deformable PS-RoI pooling. Stage 2 float2-vectorized:
// thread = (bin, channel-pair), 245 work items, 16 float2 loads each.
// ---------------------------------------------------------------------------
__global__ __launch_bounds__(256) void psroi_kernel(
    const float* __restrict__ feat, const float* __restrict__ rois,
    const float* __restrict__ om, float* __restrict__ out)
{
    int n = blockIdx.x;
    int t = threadIdx.x;

    float x1 = rois[n * 5 + 1], y1 = rois[n * 5 + 2];
    float x2 = rois[n * 5 + 3], y2 = rois[n * 5 + 4];
    float rw = x2 - x1 + 1.0f, rh = y2 - y1 + 1.0f;
    float fx1 = x1 * 0.0625f, fy1 = y1 * 0.0625f;
    float bw = (rw * 0.0625f) / 7.0f;
    float bh = (rh * 0.0625f) / 7.0f;

    __shared__ float offs[49][2];

    if (t < 49) {
        int bi = t / 7, bj = t % 7;
        float ax = 0.f, ay = 0.f;
#pragma unroll
        for (int ss = 0; ss < 4; ++ss) {
            float sj = ((float)(ss & 1) + 0.5f) * 0.5f;
            float si = ((float)(ss >> 1) + 0.5f) * 0.5f;
            float gx = fx1 + ((float)bj + sj) * bw;
            float gy = fy1 + ((float)bi + si) * bh;
            int i00, i01, i10, i11; float w00, w01, w10, w11;
            bilin_setup(gy, gx, i00, i01, i10, i11, w00, w01, w10, w11);
            int c0 = t * 2;
            const float* p00 = om + (size_t)i00 * OCN + c0;
            const float* p01 = om + (size_t)i01 * OCN + c0;
            const float* p10 = om + (size_t)i10 * OCN + c0;
            const float* p11 = om + (size_t)i11 * OCN + c0;
            ax += w00 * p00[0] + w01 * p01[0] + w10 * p10[0] + w11 * p11[0];
            ay += w00 * p00[1] + w01 * p01[1] + w10 * p10[1] + w11 * p11[1];
        }
        offs[t][0] = ax * 0.25f * rw * 0.1f * 0.0625f;
        offs[t][1] = ay * 0.25f * rh * 0.1f * 0.0625f;
    }
    __syncthreads();

    if (t < 245) {                       // 49 bins x 5 channel-pairs
        int bin = t / 5, cp = t % 5;
        int bi = bin / 7, bj = bin % 7;
        float dx = offs[bin][0], dy = offs[bin][1];
        int ch0 = bin * COUT + cp * 2;   // even -> 8B-aligned everywhere
        float accx = 0.f, accy = 0.f;
#pragma unroll
        for (int ss = 0; ss < 4; ++ss) {
            float sj = ((float)(ss & 1) + 0.5f) * 0.5f;
            float si = ((float)(ss >> 1) + 0.5f) * 0.5f;
            float gx = fx1 + ((float)bj + sj) * bw + dx;
            float gy = fy1 + ((float)bi + si) * bh + dy;
            int i00, i01, i10, i11; float w00, w01, w10, w11;
            bilin_setup(gy, gx, i00, i01, i10, i11, w00, w01, w10, w11);
            float2 v00 = *reinterpret_cast<const float2*>(feat + (size_t)i00 * CIN + ch0);
            float2 v01 = *reinterpret_cast<const float2*>(feat + (size_t)i01 * CIN + ch0);
            float2 v10 = *reinterpret_cast<const float2*>(feat + (size_t)i10 * CIN + ch0);
            float2 v11 = *reinterpret_cast<const float2*>(feat + (size_t)i11 * CIN + ch0);
            accx += w00 * v00.x + w01 * v01.x + w10 * v10.x + w11 * v11.x;
            accy += w00 * v00.y + w01 * v01.y + w10 * v10.y + w11 * v11.y;
        }
        float2 res = {accx * 0.25f, accy * 0.25f};
        *reinterpret_cast<float2*>(
            out + (size_t)n * (KK * KK * COUT) + bin * COUT + cp * 2) = res;
    }
}

extern "C" void kernel_launch(void* const* d_in, const int* in_sizes, int n_in,
                              void* d_out, int out_size, void* d_ws, size_t ws_size,
                              hipStream_t stream) {
    const float* feat = (const float*)d_in[0];   // [1,200,200,490]
    const float* rois = (const float*)d_in[1];   // [512,5]
    const float* w    = (const float*)d_in[2];   // [3,3,490,98]
    float* out = (float*)d_out;                  // [512,7,7,10]

    const size_t OM_BYTES = (size_t)NPIX * OCN * 4;                 // 15,680,000
    const size_t BP_BYTES = (size_t)NUNITS * NF * 64 * 8 * 2;       // 1,032,192
    const size_t PF_BYTES = (size_t)PH * PW * PC * 2;               // 41,783,296
    const size_t NEEDED = OM_BYTES + BP_BYTES + PF_BYTES;

    if (ws_size >= NEEDED) {
        float* om = (float*)d_ws;
        __hip_bfloat16* bp = (__hip_bfloat16*)((char*)d_ws + OM_BYTES);
        __hip_bfloat16* pf = (__hip_bfloat16*)((char*)d_ws + OM_BYTES + BP_BYTES);

        pack_all_kernel<<<FEAT_BLOCKS + W_BLOCKS, 256, 0, stream>>>(feat, w, pf, bp);
        conv_mfma_kernel<<<250, 640, 0, stream>>>(
            (const short*)pf, (const short*)bp, om);
        psroi_kernel<<<NROIS, 256, 0, stream>>>(feat, rois, om, out);
    } else {
        // fallback fp32 path
        float* zero = (float*)d_ws;
        float* om   = (float*)d_ws + 1024;
        hipMemsetAsync(d_ws, 0, 4096, stream);
        int convThreads = Hh * (Ww / PIX) * OCN;
        conv3x3_kernel<<<(convThreads + 255) / 256, 256, 0, stream>>>(feat, w, zero, om);
        psroi_kernel<<<NROIS, 256, 0, stream>>>(feat, rois, om, out);
    }
}